// Round 4
// baseline (170.280 us; speedup 1.0000x reference)
//
#include <hip/hip_runtime.h>
#include <hip/hip_bf16.h>

// Problem config (mirrors reference)
#define BB 8
#define NN 4096
#define MM 1024
#define CC 10

// Block = 256 threads = 4 waves. Wave w owns m-quarter [256w, 256w+256);
// lane l owns 4 consecutive m = 256w + 4l + {0..3}  -> one dwordx4 store
// per row per wave (1 KB per wave-instruction, fully coalesced).
// Each block processes ROWS_PER_BLOCK consecutive n-rows (all waves, same rows).
#define ROWS_PER_BLOCK 32
#define BLOCKS_PER_BATCH (NN / ROWS_PER_BLOCK)   // 128 -> grid = 1024 (fully resident at 4 blk/CU)

__device__ __forceinline__ float fast_rcp(float x) {
    float r;
    asm("v_rcp_f32 %0, %1" : "=v"(r) : "v"(x));
    return r;   // ~1 ulp; iou error ~1e-7, negligible vs absmax budget
}

__global__ __launch_bounds__(256, 4)
void transfusion_cost_kernel(const float* __restrict__ bboxes,      // [B,N,7]
                             const float* __restrict__ gt_bboxes,   // [B,M,7]
                             const float* __restrict__ cls_pred,    // [B,N,C]
                             const int*   __restrict__ gt_labels,   // [B,M]
                             float* __restrict__ out)               // [B,N,M]
{
    const int tid  = threadIdx.x;
    const int lane = tid & 63;
    const int wave = tid >> 6;                 // m-quarter index 0..3

    const int b  = blockIdx.x / BLOCKS_PER_BATCH;
    const int n0 = (blockIdx.x % BLOCKS_PER_BATCH) * ROWS_PER_BLOCK;

    const float SCL = 0.25f / 108.0f;          // REG_W folded into xy normalization

    // ---- per-lane gt state: 4 consecutive m, loaded once per block ----
    const int m0 = wave * 256 + 4 * lane;
    const float* gtb = gt_bboxes + ((size_t)b * MM + m0) * 7;
    const int*   gtl = gt_labels + (size_t)b * MM + m0;

    float gx1[4], gy1[4], gx2[4], gy2[4], areaB[4], bxs[4], bys[4];
    int   lbl[4];
#pragma unroll
    for (int j = 0; j < 4; ++j) {
        const float* g = gtb + j * 7;
        const float x  = g[0];
        const float y  = g[1];
        const float dx = g[3];
        const float dy = g[4];
        const float x1 = x - 0.5f * dx, x2 = x + 0.5f * dx;
        const float y1 = y - 0.5f * dy, y2 = y + 0.5f * dy;
        gx1[j] = x1; gy1[j] = y1; gx2[j] = x2; gy2[j] = y2;
        areaB[j] = fmaxf(x2 - x1, 0.0f) * fmaxf(y2 - y1, 0.0f);
        bxs[j] = (x + 54.0f) * SCL;
        bys[j] = (y + 54.0f) * SCL;
        lbl[j] = gtl[j];
    }

    const int c = (lane < CC) ? lane : 0;      // focal channel this lane evaluates
    const float* arow = bboxes   + ((size_t)b * NN + n0) * 7;
    const float* crow = cls_pred + ((size_t)b * NN + n0) * CC;
    float*       orow = out + ((size_t)b * NN + n0) * MM + m0;

    // ---- row loop ----
#pragma unroll 2
    for (int r = 0; r < ROWS_PER_BLOCK; ++r) {
        const float* a = arow + r * 7;
        const float ax  = a[0];
        const float ay  = a[1];
        const float adx = a[3];
        const float ady = a[4];
        const float logit = crow[r * CC + c];

        const float xa1 = ax - 0.5f * adx, xa2 = ax + 0.5f * adx;
        const float ya1 = ay - 0.5f * ady, ya2 = ay + 0.5f * ady;
        const float areaA = fmaxf(xa2 - xa1, 0.0f) * fmaxf(ya2 - ya1, 0.0f);
        const float axs = (ax + 54.0f) * SCL;
        const float ays = (ay + 54.0f) * SCL;

        // focal diff for channel == lane (numerics identical to r1 — don't perturb absmax)
        const float p   = 1.0f / (1.0f + expf(-logit));
        const float omp = 1.0f - p;
        const float pos = -logf(p   + 1e-12f) * 0.25f * omp * omp;
        const float neg = -logf(omp + 1e-12f) * 0.75f * p * p;
        const float dval = (pos - neg) * 0.15f;

        float vv[4];
#pragma unroll
        for (int j = 0; j < 4; ++j) {
            const float ix1 = fmaxf(xa1, gx1[j]);
            const float iy1 = fmaxf(ya1, gy1[j]);
            const float ix2 = fminf(xa2, gx2[j]);
            const float iy2 = fminf(ya2, gy2[j]);
            const float iw  = fmaxf(ix2 - ix1, 0.0f);
            const float ih  = fmaxf(iy2 - iy1, 0.0f);
            const float inter = iw * ih;
            const float uni   = areaA + areaB[j] - inter;
            const float iou   = inter * fast_rcp(fmaxf(uni, 1e-6f));

            const float cls = __shfl(dval, lbl[j], 64);
            const float reg = fabsf(axs - bxs[j]) + fabsf(ays - bys[j]);

            vv[j] = cls + reg - 0.25f * iou;
        }

        *reinterpret_cast<float4*>(orow + (size_t)r * MM) =
            make_float4(vv[0], vv[1], vv[2], vv[3]);
    }
}

extern "C" void kernel_launch(void* const* d_in, const int* in_sizes, int n_in,
                              void* d_out, int out_size, void* d_ws, size_t ws_size,
                              hipStream_t stream) {
    const float* bboxes    = (const float*)d_in[0];
    const float* gt_bboxes = (const float*)d_in[1];
    const float* cls_pred  = (const float*)d_in[2];
    const int*   gt_labels = (const int*)d_in[3];
    float* out = (float*)d_out;

    const int grid = BB * BLOCKS_PER_BATCH;   // 1024 blocks, 256 threads
    transfusion_cost_kernel<<<grid, 256, 0, stream>>>(bboxes, gt_bboxes, cls_pred,
                                                      gt_labels, out);
}